// Round 2
// baseline (230.641 us; speedup 1.0000x reference)
//
#include <hip/hip_runtime.h>
#include <hip/hip_bf16.h>

#define N_Q    4
#define SEQ    4096
#define EMB    512
#define TAGS   64
#define INV2PI 0.15915494309189535f
#define CHUNK  128
#define WARM   96
#define NCHUNK (SEQ / CHUNK)   // 32

// ---- workspace layout (float offsets) ----
// WT : [16][512] prescaled W columns   off 0      size 8192
// bb : [16]      prescaled biases      off 8192   size 16
// xp : [4100][16] x-part preacts (rev) off 8208   size 65600 (padded +4 steps for prefetch)
// hs : [4096][4] hidden states         off 73808  size 16384
#define WS_WT 0
#define WS_BB 8192
#define WS_XP 8208
#define WS_HS 73808

// DPP helper: update_dpp on float via bitcast. Masked-out lanes keep OLD.
#define DPPF(OLD, SRC, CTRL, RM, BM) \
  __int_as_float(__builtin_amdgcn_update_dpp(__float_as_int(OLD), __float_as_int(SRC), (CTRL), (RM), (BM), false))

// ---------------- K0: build transposed/prescaled W columns ----------------
__global__ __launch_bounds__(256) void k0_wt(
    const float* __restrict__ Wf, const float* __restrict__ Wi,
    const float* __restrict__ Wu, const float* __restrict__ Wo,
    const float* __restrict__ bf, const float* __restrict__ bi,
    const float* __restrict__ bu, const float* __restrict__ bo,
    float* __restrict__ WT, float* __restrict__ bb)
{
  int tid = blockIdx.x * blockDim.x + threadIdx.x;   // 0..8191
  int c = tid >> 9;          // column 0..15 = g*4+k
  int e = tid & 511;
  int g = c >> 2, k = c & 3;
  const float* W = (g == 0) ? Wf : (g == 1) ? Wi : (g == 2) ? Wu : Wo;
  WT[c * EMB + e] = W[e * 4 + k] * INV2PI;
  if (tid < 16) {
    int g2 = tid >> 2, k2 = tid & 3;
    const float* b = (g2 == 0) ? bf : (g2 == 1) ? bi : (g2 == 2) ? bu : bo;
    bb[tid] = b[k2] * INV2PI;
  }
}

// ---------------- K1: xpart[t][p] = (emb[sent[t]] . Wcol + b) / 2pi ------
__global__ __launch_bounds__(256) void k1_xp(
    const int* __restrict__ sent, const float* __restrict__ emb,
    const float* __restrict__ WT, const float* __restrict__ bb,
    float* __restrict__ xp)
{
  int idx = blockIdx.x * 256 + threadIdx.x;   // 0..65535
  int t = idx >> 4;
  int c = idx & 15;                           // c = g*4+k
  const float4* x = (const float4*)(emb + (size_t)sent[t] * EMB);
  const float4* w = (const float4*)(WT + c * EMB);
  float a0 = 0.f, a1 = 0.f, a2 = 0.f, a3 = 0.f;
#pragma unroll 8
  for (int e4 = 0; e4 < EMB / 4; ++e4) {
    float4 xv = x[e4];
    float4 wv = w[e4];
    a0 = fmaf(xv.x, wv.x, a0);
    a1 = fmaf(xv.y, wv.y, a1);
    a2 = fmaf(xv.z, wv.z, a2);
    a3 = fmaf(xv.w, wv.w, a3);
  }
  float dot = (a0 + a1) + (a2 + a3) + bb[c];
  // store at position p = k*4+g so that lane p of k2 reads its own value
  int p = ((c & 3) << 2) | (c >> 2);
  xp[t * 16 + p] = dot;
}

// ---------------- K2: the recurrence, chunk-parallel, DPP lane layout ----
// lane p = k*4+g : component k = p>>2, gate g = p&3 (f,i,u,o)
__global__ __launch_bounds__(64) void k2_rec(
    const float* __restrict__ xp,
    const float* __restrict__ Wf, const float* __restrict__ Wi,
    const float* __restrict__ Wu, const float* __restrict__ Wo,
    const float* __restrict__ qf, const float* __restrict__ qi,
    const float* __restrict__ qu, const float* __restrict__ qo,
    float* __restrict__ hs)
{
  const int lane = threadIdx.x & 63;
  const int p = lane & 15;
  const int k = p >> 2;
  const int g = p & 3;
  const float* W = (g == 0) ? Wf : (g == 1) ? Wi : (g == 2) ? Wu : Wo;
  const float* q = (g == 0) ? qf : (g == 1) ? qi : (g == 2) ? qu : qo;

  // hx-coefficients: wh[m] = W[(512+m)*4 + k] / 2pi   (column k of own gate)
  float wh0 = W[(EMB + 0) * 4 + k] * INV2PI;
  float wh1 = W[(EMB + 1) * 4 + k] * INV2PI;
  float wh2 = W[(EMB + 2) * 4 + k] * INV2PI;
  float wh3 = W[(EMB + 3) * 4 + k] * INV2PI;

  // probe which component arrives via each row_ror (direction-robust)
  int s1i = __builtin_amdgcn_update_dpp(k, k, 0x124, 0xF, 0xF, false); // ror 4
  int s2i = __builtin_amdgcn_update_dpp(k, k, 0x128, 0xF, 0xF, false); // ror 8
  int s3i = __builtin_amdgcn_update_dpp(k, k, 0x12C, 0xF, 0xF, false); // ror 12
  #define SELW(KK) ((KK) == 0 ? wh0 : (KK) == 1 ? wh1 : (KK) == 2 ? wh2 : wh3)
  float W0 = SELW(k);
  float W1 = SELW(s1i);
  float W2 = SELW(s2i);
  float W3 = SELW(s3i);

  // cumulative cos(q) product up to own k
  float cc0 = cosf(q[0]);
  float cc1 = cc0 * cosf(q[1]);
  float cc2 = cc1 * cosf(q[2]);
  float cc3 = cc2 * cosf(q[3]);
  float cq = (k == 0) ? cc0 : (k == 1) ? cc1 : (k == 2) ? cc2 : cc3;

  // odd-poly nonlinearity coeffs (sigmoid for f,i,o; tanh for u), cq folded in
  float P0, P1, P2, P3, D;
  if (g == 2) { // tanh, max err ~2e-4 on [-1,1]
    P0 = 0.99990143f; P1 = -0.33104735f; P2 = 0.12044012f; P3 = -0.02770000f; D = 0.0f;
  } else {      // sigmoid Taylor deg-7, max err ~2e-5 on [-1,1]
    P0 = 0.25f; P1 = -0.020833334f; P2 = 0.0020833334f; P3 = -2.1081349e-4f; D = 0.5f;
  }
  float cq2 = cq * cq;
  float K0c = P0 * cq;
  float K1c = P1 * cq * cq2;
  float K2c = P2 * cq * cq2 * cq2;
  float K3c = P3 * cq * cq2 * cq2 * cq2;

  // chunk range (warmup from zero state; contraction f<=sigma(1)=0.731)
  int c_id = blockIdx.x;
  int t_real = c_id * CHUNK;
  int t0 = t_real - WARM; if (t0 < 0) t0 = 0;
  int t_end = t_real + CHUNK;

  const float* base = xp + p;
  float xb0 = base[t0 * 16];
  float xb1 = base[(t0 + 1) * 16];
  float xb2 = base[(t0 + 2) * 16];

  float hx = 0.f, cx = 0.f;
  const float one = 1.0f;

  for (int t = t0; t < t_end; ++t) {
    float xpv = xb0; xb0 = xb1; xb1 = xb2;
    xb2 = base[(t + 3) * 16];            // padded overread, value unused past end

    // ang (revolutions) = xp + sum_m hx_m * wh_m, via quad rotations
    float r1 = DPPF(hx, hx, 0x124, 0xF, 0xF);
    float r2 = DPPF(hx, hx, 0x128, 0xF, 0xF);
    float r3 = DPPF(hx, hx, 0x12C, 0xF, 0xF);
    float ang = fmaf(hx, W0, xpv);
    ang = fmaf(r1, W1, ang);
    ang = fmaf(r2, W2, ang);
    ang = fmaf(r3, W3, ang);

    float cv = __builtin_amdgcn_cosf(ang);   // input in revolutions

    // segmented prefix product over k (quads within row16): row_shr 4 then 8
    float sA = DPPF(one, cv, 0x114, 0xF, 0xE);   // k==0 lanes keep 1.0
    float m1 = cv * sA;
    float sB = DPPF(one, m1, 0x118, 0xF, 0xC);   // k<2 lanes keep 1.0
    float m  = m1 * sB;

    // gate value: v = D + m*(K0 + y*(K1 + y*(K2 + y*K3))), y = m^2
    float y = m * m;
    float pp = fmaf(y, K3c, K2c);
    pp = fmaf(y, pp, K1c);
    pp = fmaf(y, pp, K0c);
    float v = fmaf(m, pp, D);

    // gather f,i,u,o within quad (quad = fixed k, lanes g=0..3)
    float vf = DPPF(v, v, 0x00, 0xF, 0xF);
    float vi = DPPF(v, v, 0x55, 0xF, 0xF);
    float vu = DPPF(v, v, 0xAA, 0xF, 0xF);
    float vo = DPPF(v, v, 0xFF, 0xF, 0xF);

    cx = fmaf(vf, cx, vi * vu);

    // hx = o * tanh(cx); tanh(cx) = 1 - 2/(e^{2cx}+1), rr = 1/(e^{2cx}+1)
    float e2 = __builtin_amdgcn_exp2f(2.885390082f * cx);
    float rr = __builtin_amdgcn_rcpf(e2 + 1.0f);
    hx = fmaf(-2.0f * vo, rr, vo);

    if (t >= t_real) hs[t * 4 + k] = hx;   // replicated lanes write same value
  }
}

// ---------------- K3: logits + log_softmax (64 tags = 1 wave/row) --------
__global__ __launch_bounds__(256) void k3_out(
    const float* __restrict__ hs, const float* __restrict__ Wt,
    const float* __restrict__ bt, float* __restrict__ out)
{
  int t = blockIdx.x * 4 + (threadIdx.x >> 6);
  int j = threadIdx.x & 63;
  float4 h = *(const float4*)(hs + t * 4);
  float z = bt[j];
  z = fmaf(h.x, Wt[j],       z);
  z = fmaf(h.y, Wt[64 + j],  z);
  z = fmaf(h.z, Wt[128 + j], z);
  z = fmaf(h.w, Wt[192 + j], z);
  // |z| <= ~4 (|h|<=tanh(1), Wt ~ 0.5*N(0,1)) -> exp safe without max-sub
  float e = __builtin_amdgcn_exp2f(z * 1.4426950408889634f);
  float s = e;
#pragma unroll
  for (int off = 32; off > 0; off >>= 1) s += __shfl_xor(s, off, 64);
  out[t * 64 + j] = z - __builtin_amdgcn_logf(s) * 0.69314718055994531f;
}

extern "C" void kernel_launch(void* const* d_in, const int* in_sizes, int n_in,
                              void* d_out, int out_size, void* d_ws, size_t ws_size,
                              hipStream_t stream) {
  (void)in_sizes; (void)n_in; (void)out_size; (void)ws_size;
  const int*   sent = (const int*)  d_in[0];
  const float* emb  = (const float*)d_in[1];
  const float* Wf   = (const float*)d_in[2];
  const float* bf   = (const float*)d_in[3];
  const float* Wi   = (const float*)d_in[4];
  const float* bi   = (const float*)d_in[5];
  const float* Wu   = (const float*)d_in[6];
  const float* bu   = (const float*)d_in[7];
  const float* Wo   = (const float*)d_in[8];
  const float* bo   = (const float*)d_in[9];
  const float* qf   = (const float*)d_in[10];
  const float* qi   = (const float*)d_in[11];
  const float* qu   = (const float*)d_in[12];
  const float* qo   = (const float*)d_in[13];
  const float* Wt   = (const float*)d_in[14];
  const float* bt   = (const float*)d_in[15];

  float* ws = (float*)d_ws;
  float* WT = ws + WS_WT;
  float* bb = ws + WS_BB;
  float* xp = ws + WS_XP;
  float* hs = ws + WS_HS;
  float* out = (float*)d_out;

  k0_wt<<<dim3(32),   dim3(256), 0, stream>>>(Wf, Wi, Wu, Wo, bf, bi, bu, bo, WT, bb);
  k1_xp<<<dim3(256),  dim3(256), 0, stream>>>(sent, emb, WT, bb, xp);
  k2_rec<<<dim3(NCHUNK), dim3(64), 0, stream>>>(xp, Wf, Wi, Wu, Wo, qf, qi, qu, qo, hs);
  k3_out<<<dim3(1024), dim3(256), 0, stream>>>(hs, Wt, bt, out);
}

// Round 3
// 194.292 us; speedup vs baseline: 1.1871x; 1.1871x over previous
//
#include <hip/hip_runtime.h>
#include <hip/hip_bf16.h>

#define N_Q    4
#define SEQ    4096
#define EMB    512
#define TAGS   64
#define INV2PI 0.15915494309189535f
#define CHUNK  32
#define WARM   32
#define NCHUNK (SEQ / CHUNK)   // 128

// ---- workspace layout (float offsets) ----
// WT : [16][512] prescaled W columns   off 0      size 8192
// bb : [16]      prescaled biases      off 8192   size 16
// xp : [4100][16] x-part preacts (rev) off 8208   size 65600 (padded +4 steps for prefetch)
// hs : [4096][4] hidden states         off 73808  size 16384
#define WS_WT 0
#define WS_BB 8192
#define WS_XP 8208
#define WS_HS 73808

// DPP helper: update_dpp on float via bitcast. Masked-out lanes keep OLD.
#define DPPF(OLD, SRC, CTRL, RM, BM) \
  __int_as_float(__builtin_amdgcn_update_dpp(__float_as_int(OLD), __float_as_int(SRC), (CTRL), (RM), (BM), false))

// ---------------- K0: build transposed/prescaled W columns ----------------
__global__ __launch_bounds__(256) void k0_wt(
    const float* __restrict__ Wf, const float* __restrict__ Wi,
    const float* __restrict__ Wu, const float* __restrict__ Wo,
    const float* __restrict__ bf, const float* __restrict__ bi,
    const float* __restrict__ bu, const float* __restrict__ bo,
    float* __restrict__ WT, float* __restrict__ bb)
{
  int tid = blockIdx.x * blockDim.x + threadIdx.x;   // 0..8191
  int c = tid >> 9;          // column 0..15 = g*4+k
  int e = tid & 511;
  int g = c >> 2, k = c & 3;
  const float* W = (g == 0) ? Wf : (g == 1) ? Wi : (g == 2) ? Wu : Wo;
  WT[c * EMB + e] = W[e * 4 + k] * INV2PI;
  if (tid < 16) {
    int g2 = tid >> 2, k2 = tid & 3;
    const float* b = (g2 == 0) ? bf : (g2 == 1) ? bi : (g2 == 2) ? bu : bo;
    bb[tid] = b[k2] * INV2PI;
  }
}

// ---------------- K1: xpart[t][p] = (emb[sent[t]] . Wcol + b) / 2pi ------
__global__ __launch_bounds__(256) void k1_xp(
    const int* __restrict__ sent, const float* __restrict__ emb,
    const float* __restrict__ WT, const float* __restrict__ bb,
    float* __restrict__ xp)
{
  int idx = blockIdx.x * 256 + threadIdx.x;   // 0..65535
  int t = idx >> 4;
  int c = idx & 15;                           // c = g*4+k
  const float4* x = (const float4*)(emb + (size_t)sent[t] * EMB);
  const float4* w = (const float4*)(WT + c * EMB);
  float a0 = 0.f, a1 = 0.f, a2 = 0.f, a3 = 0.f;
#pragma unroll 8
  for (int e4 = 0; e4 < EMB / 4; ++e4) {
    float4 xv = x[e4];
    float4 wv = w[e4];
    a0 = fmaf(xv.x, wv.x, a0);
    a1 = fmaf(xv.y, wv.y, a1);
    a2 = fmaf(xv.z, wv.z, a2);
    a3 = fmaf(xv.w, wv.w, a3);
  }
  float dot = (a0 + a1) + (a2 + a3) + bb[c];
  // store at position p = k*4+g so that lane p of k2 reads its own value
  int p = ((c & 3) << 2) | (c >> 2);
  xp[t * 16 + p] = dot;
}

// ---------------- K2: the recurrence, chunk-parallel, DPP lane layout ----
// lane p = k*4+g : component k = p>>2, gate g = p&3 (f,i,u,o)
__global__ __launch_bounds__(64) void k2_rec(
    const float* __restrict__ xp,
    const float* __restrict__ Wf, const float* __restrict__ Wi,
    const float* __restrict__ Wu, const float* __restrict__ Wo,
    const float* __restrict__ qf, const float* __restrict__ qi,
    const float* __restrict__ qu, const float* __restrict__ qo,
    float* __restrict__ hs)
{
  const int lane = threadIdx.x & 63;
  const int p = lane & 15;
  const int k = p >> 2;
  const int g = p & 3;
  const float* W = (g == 0) ? Wf : (g == 1) ? Wi : (g == 2) ? Wu : Wo;
  const float* q = (g == 0) ? qf : (g == 1) ? qi : (g == 2) ? qu : qo;

  // hx-coefficients: wh[m] = W[(512+m)*4 + k] / 2pi   (column k of own gate)
  float wh0 = W[(EMB + 0) * 4 + k] * INV2PI;
  float wh1 = W[(EMB + 1) * 4 + k] * INV2PI;
  float wh2 = W[(EMB + 2) * 4 + k] * INV2PI;
  float wh3 = W[(EMB + 3) * 4 + k] * INV2PI;

  // probe which component arrives via each row_ror (direction-robust)
  int s1i = __builtin_amdgcn_update_dpp(k, k, 0x124, 0xF, 0xF, false); // ror 4
  int s2i = __builtin_amdgcn_update_dpp(k, k, 0x128, 0xF, 0xF, false); // ror 8
  int s3i = __builtin_amdgcn_update_dpp(k, k, 0x12C, 0xF, 0xF, false); // ror 12
  #define SELW(KK) ((KK) == 0 ? wh0 : (KK) == 1 ? wh1 : (KK) == 2 ? wh2 : wh3)
  float W0 = SELW(k);
  float W1 = SELW(s1i);
  float W2 = SELW(s2i);
  float W3 = SELW(s3i);

  // cumulative cos(q) product up to own k
  float cc0 = cosf(q[0]);
  float cc1 = cc0 * cosf(q[1]);
  float cc2 = cc1 * cosf(q[2]);
  float cc3 = cc2 * cosf(q[3]);
  float cq = (k == 0) ? cc0 : (k == 1) ? cc1 : (k == 2) ? cc2 : cc3;

  // odd-poly nonlinearity coeffs (sigmoid for f,i,o; tanh for u), cq folded in
  float P0, P1, P2, P3, D;
  if (g == 2) { // tanh, max err ~2e-4 on [-1,1]
    P0 = 0.99990143f; P1 = -0.33104735f; P2 = 0.12044012f; P3 = -0.02770000f; D = 0.0f;
  } else {      // sigmoid Taylor deg-7, max err ~2e-5 on [-1,1]
    P0 = 0.25f; P1 = -0.020833334f; P2 = 0.0020833334f; P3 = -2.1081349e-4f; D = 0.5f;
  }
  float cq2 = cq * cq;
  float K0c = P0 * cq;
  float K1c = P1 * cq * cq2;
  float K2c = P2 * cq * cq2 * cq2;
  float K3c = P3 * cq * cq2 * cq2 * cq2;

  // chunk range (warmup from zero state; contraction f<=sigma(1)=0.731,
  // cx init error <=2.07 decays to 2.07*0.731^32 ~ 9e-5 -> logit err ~1e-4)
  int c_id = blockIdx.x;
  int t_real = c_id * CHUNK;
  int t0 = t_real - WARM; if (t0 < 0) t0 = 0;
  int t_end = t_real + CHUNK;

  const float* base = xp + p;
  float xb0 = base[t0 * 16];
  float xb1 = base[(t0 + 1) * 16];
  float xb2 = base[(t0 + 2) * 16];

  float hx = 0.f, cx = 0.f;
  const float one = 1.0f;

  for (int t = t0; t < t_end; ++t) {
    float xpv = xb0; xb0 = xb1; xb1 = xb2;
    xb2 = base[(t + 3) * 16];            // padded overread, value unused past end

    // ang (revolutions) = xp + sum_m hx_m * wh_m, via quad rotations (tree)
    float r1 = DPPF(hx, hx, 0x124, 0xF, 0xF);
    float r2 = DPPF(hx, hx, 0x128, 0xF, 0xF);
    float r3 = DPPF(hx, hx, 0x12C, 0xF, 0xF);
    float A1 = fmaf(hx, W0, xpv);
    float B1 = r1 * W1;
    float A2 = fmaf(r2, W2, A1);
    float B2 = fmaf(r3, W3, B1);
    float ang = A2 + B2;

    float cv = __builtin_amdgcn_cosf(ang);   // input in revolutions

    // segmented prefix product over k (quads within row16): row_shr 4 then 8
    float sA = DPPF(one, cv, 0x114, 0xF, 0xE);   // k==0 lanes keep 1.0
    float m1 = cv * sA;
    float sB = DPPF(one, m1, 0x118, 0xF, 0xC);   // k<2 lanes keep 1.0
    float m  = m1 * sB;

    // gate value: v = D + m*(K0 + y*(K1 + y*(K2 + y*K3))), y = m^2
    float y = m * m;
    float pp = fmaf(y, K3c, K2c);
    pp = fmaf(y, pp, K1c);
    pp = fmaf(y, pp, K0c);
    float v = fmaf(m, pp, D);

    // gather f,i,u,o within quad (quad = fixed k, lanes g=0..3)
    float vf = DPPF(v, v, 0x00, 0xF, 0xF);
    float vi = DPPF(v, v, 0x55, 0xF, 0xF);
    float vu = DPPF(v, v, 0xAA, 0xF, 0xF);
    float vo = DPPF(v, v, 0xFF, 0xF, 0xF);

    cx = fmaf(vf, cx, vi * vu);

    // hx = o * tanh(cx); tanh(cx) = 1 - 2/(e^{2cx}+1), rr = 1/(e^{2cx}+1)
    float e2 = __builtin_amdgcn_exp2f(2.885390082f * cx);
    float rr = __builtin_amdgcn_rcpf(e2 + 1.0f);
    hx = fmaf(-2.0f * vo, rr, vo);

    if (t >= t_real) hs[t * 4 + k] = hx;   // replicated lanes write same value
  }
}

// ---------------- K3: logits + log_softmax (64 tags = 1 wave/row) --------
__global__ __launch_bounds__(256) void k3_out(
    const float* __restrict__ hs, const float* __restrict__ Wt,
    const float* __restrict__ bt, float* __restrict__ out)
{
  int t = blockIdx.x * 4 + (threadIdx.x >> 6);
  int j = threadIdx.x & 63;
  float4 h = *(const float4*)(hs + t * 4);
  float z = bt[j];
  z = fmaf(h.x, Wt[j],       z);
  z = fmaf(h.y, Wt[64 + j],  z);
  z = fmaf(h.z, Wt[128 + j], z);
  z = fmaf(h.w, Wt[192 + j], z);
  // |z| <= ~4 (|h|<=tanh(1), Wt ~ 0.5*N(0,1)) -> exp safe without max-sub
  float e = __builtin_amdgcn_exp2f(z * 1.4426950408889634f);
  float s = e;
#pragma unroll
  for (int off = 32; off > 0; off >>= 1) s += __shfl_xor(s, off, 64);
  out[t * 64 + j] = z - __builtin_amdgcn_logf(s) * 0.69314718055994531f;
}

extern "C" void kernel_launch(void* const* d_in, const int* in_sizes, int n_in,
                              void* d_out, int out_size, void* d_ws, size_t ws_size,
                              hipStream_t stream) {
  (void)in_sizes; (void)n_in; (void)out_size; (void)ws_size;
  const int*   sent = (const int*)  d_in[0];
  const float* emb  = (const float*)d_in[1];
  const float* Wf   = (const float*)d_in[2];
  const float* bf   = (const float*)d_in[3];
  const float* Wi   = (const float*)d_in[4];
  const float* bi   = (const float*)d_in[5];
  const float* Wu   = (const float*)d_in[6];
  const float* bu   = (const float*)d_in[7];
  const float* Wo   = (const float*)d_in[8];
  const float* bo   = (const float*)d_in[9];
  const float* qf   = (const float*)d_in[10];
  const float* qi   = (const float*)d_in[11];
  const float* qu   = (const float*)d_in[12];
  const float* qo   = (const float*)d_in[13];
  const float* Wt   = (const float*)d_in[14];
  const float* bt   = (const float*)d_in[15];

  float* ws = (float*)d_ws;
  float* WT = ws + WS_WT;
  float* bb = ws + WS_BB;
  float* xp = ws + WS_XP;
  float* hs = ws + WS_HS;
  float* out = (float*)d_out;

  k0_wt<<<dim3(32),   dim3(256), 0, stream>>>(Wf, Wi, Wu, Wo, bf, bi, bu, bo, WT, bb);
  k1_xp<<<dim3(256),  dim3(256), 0, stream>>>(sent, emb, WT, bb, xp);
  k2_rec<<<dim3(NCHUNK), dim3(64), 0, stream>>>(xp, Wf, Wi, Wu, Wo, qf, qi, qu, qo, hs);
  k3_out<<<dim3(1024), dim3(256), 0, stream>>>(hs, Wt, bt, out);
}

// Round 4
// 180.758 us; speedup vs baseline: 1.2760x; 1.0749x over previous
//
#include <hip/hip_runtime.h>
#include <hip/hip_bf16.h>

#define N_Q    4
#define SEQ    4096
#define EMB    512
#define TAGS   64
#define INV2PI 0.15915494309189535f
#define CHUNK  16
#define WARM   24
#define NCHUNK (SEQ / CHUNK)   // 256

// ---- workspace layout (float offsets) ----
// xp : [4100][16] x-part preacts (revolutions), padded +4 steps for prefetch
#define WS_XP 0

// DPP helper: update_dpp on float via bitcast. Masked-out lanes keep OLD.
#define DPPF(OLD, SRC, CTRL, RM, BM) \
  __int_as_float(__builtin_amdgcn_update_dpp(__float_as_int(OLD), __float_as_int(SRC), (CTRL), (RM), (BM), false))

// ---------------- K1: xpart[t][p] = (emb[sent[t]] . Wcol + b) / 2pi ------
// One block = 16 timesteps x 16 columns. W staged to LDS (stride 516: 2-way
// bank aliasing only = free), scale folded into the store.
__global__ __launch_bounds__(256) void k1_xp(
    const int* __restrict__ sent, const float* __restrict__ emb,
    const float* __restrict__ Wf, const float* __restrict__ Wi,
    const float* __restrict__ Wu, const float* __restrict__ Wo,
    const float* __restrict__ bf, const float* __restrict__ bi,
    const float* __restrict__ bu, const float* __restrict__ bo,
    float* __restrict__ xp)
{
  __shared__ float colbuf[16 * 516];   // 33 KB
  int tid = threadIdx.x;
#pragma unroll
  for (int g = 0; g < 4; ++g) {
    const float* W = (g == 0) ? Wf : (g == 1) ? Wi : (g == 2) ? Wu : Wo;
#pragma unroll
    for (int half = 0; half < 2; ++half) {
      int e = tid + half * 256;
      float4 r = *(const float4*)(W + e * 4);   // row e, all 4 cols
      colbuf[(g * 4 + 0) * 516 + e] = r.x;
      colbuf[(g * 4 + 1) * 516 + e] = r.y;
      colbuf[(g * 4 + 2) * 516 + e] = r.z;
      colbuf[(g * 4 + 3) * 516 + e] = r.w;
    }
  }
  __syncthreads();

  int t = blockIdx.x * 16 + (tid >> 4);
  int c = tid & 15;                    // c = g*4+k
  int g = c >> 2, k = c & 3;
  const float4* x = (const float4*)(emb + (size_t)sent[t] * EMB);
  const float4* w = (const float4*)(&colbuf[c * 516]);   // 16B-aligned (516*4=2064)
  float a0 = 0.f, a1 = 0.f, a2 = 0.f, a3 = 0.f;
#pragma unroll 8
  for (int e4 = 0; e4 < EMB / 4; ++e4) {
    float4 xv = x[e4];
    float4 wv = w[e4];
    a0 = fmaf(xv.x, wv.x, a0);
    a1 = fmaf(xv.y, wv.y, a1);
    a2 = fmaf(xv.z, wv.z, a2);
    a3 = fmaf(xv.w, wv.w, a3);
  }
  const float* b = (g == 0) ? bf : (g == 1) ? bi : (g == 2) ? bu : bo;
  float dot = ((a0 + a1) + (a2 + a3) + b[k]) * INV2PI;
  // store at position p = k*4+g so that lane p of k2 reads its own value
  int p = ((c & 3) << 2) | (c >> 2);
  xp[t * 16 + p] = dot;
}

// ---------------- K2: recurrence + fused logits/log_softmax epilogue -----
// lane p = k*4+g : component k = p>>2, gate g = p&3 (f,i,u,o)
__global__ __launch_bounds__(64) void k2_rec(
    const float* __restrict__ xp,
    const float* __restrict__ Wf, const float* __restrict__ Wi,
    const float* __restrict__ Wu, const float* __restrict__ Wo,
    const float* __restrict__ qf, const float* __restrict__ qi,
    const float* __restrict__ qu, const float* __restrict__ qo,
    const float* __restrict__ Wt, const float* __restrict__ bt,
    float* __restrict__ out)
{
  __shared__ float hsh[CHUNK * 4];
  const int lane = threadIdx.x & 63;
  const int p = lane & 15;
  const int k = p >> 2;
  const int g = p & 3;
  const float* W = (g == 0) ? Wf : (g == 1) ? Wi : (g == 2) ? Wu : Wo;
  const float* q = (g == 0) ? qf : (g == 1) ? qi : (g == 2) ? qu : qo;

  // epilogue constants (independent loads, hidden under recurrence)
  float wt0 = Wt[lane], wt1 = Wt[64 + lane], wt2 = Wt[128 + lane], wt3 = Wt[192 + lane];
  float bj = bt[lane];

  // hx-coefficients: wh[m] = W[(512+m)*4 + k] / 2pi   (column k of own gate)
  float wh0 = W[(EMB + 0) * 4 + k] * INV2PI;
  float wh1 = W[(EMB + 1) * 4 + k] * INV2PI;
  float wh2 = W[(EMB + 2) * 4 + k] * INV2PI;
  float wh3 = W[(EMB + 3) * 4 + k] * INV2PI;

  // probe which component arrives via each row_ror (direction-robust)
  int s1i = __builtin_amdgcn_update_dpp(k, k, 0x124, 0xF, 0xF, false); // ror 4
  int s2i = __builtin_amdgcn_update_dpp(k, k, 0x128, 0xF, 0xF, false); // ror 8
  int s3i = __builtin_amdgcn_update_dpp(k, k, 0x12C, 0xF, 0xF, false); // ror 12
  #define SELW(KK) ((KK) == 0 ? wh0 : (KK) == 1 ? wh1 : (KK) == 2 ? wh2 : wh3)
  float W0 = SELW(k);
  float W1 = SELW(s1i);
  float W2 = SELW(s2i);
  float W3 = SELW(s3i);

  // cumulative cos(q) product up to own k
  float cc0 = cosf(q[0]);
  float cc1 = cc0 * cosf(q[1]);
  float cc2 = cc1 * cosf(q[2]);
  float cc3 = cc2 * cosf(q[3]);
  float cq = (k == 0) ? cc0 : (k == 1) ? cc1 : (k == 2) ? cc2 : cc3;

  // odd-poly nonlinearity coeffs (sigmoid for f,i,o; tanh for u), cq folded in
  float P0, P1, P2, P3, D;
  if (g == 2) { // tanh, max err ~2e-4 on [-1,1]
    P0 = 0.99990143f; P1 = -0.33104735f; P2 = 0.12044012f; P3 = -0.02770000f; D = 0.0f;
  } else {      // sigmoid Taylor deg-7, max err ~2e-5 on [-1,1]
    P0 = 0.25f; P1 = -0.020833334f; P2 = 0.0020833334f; P3 = -2.1081349e-4f; D = 0.5f;
  }
  float cq2 = cq * cq;
  float K0c = P0 * cq;
  float K1c = P1 * cq * cq2;
  float K2c = P2 * cq * cq2 * cq2;
  float K3c = P3 * cq * cq2 * cq2 * cq2;

  // chunk range (warmup from zero state; contraction f<=sigma(1)=0.731:
  // cx init err <=2.07 decays to 2.07*0.731^24 ~ 1.1e-3 -> logit err ~3e-3)
  int c_id = blockIdx.x;
  int t_real = c_id * CHUNK;
  int t0 = t_real - WARM; if (t0 < 0) t0 = 0;
  int t_end = t_real + CHUNK;

  const float* base = xp + p;
  float xb0 = base[t0 * 16];
  float xb1 = base[(t0 + 1) * 16];
  float xb2 = base[(t0 + 2) * 16];

  float hx = 0.f, cx = 0.f;
  const float one = 1.0f;

  for (int t = t0; t < t_end; ++t) {
    float xpv = xb0; xb0 = xb1; xb1 = xb2;
    xb2 = base[(t + 3) * 16];            // padded overread, value unused past end

    // ang (revolutions) = xp + sum_m hx_m * wh_m, via quad rotations (tree)
    float r1 = DPPF(hx, hx, 0x124, 0xF, 0xF);
    float r2 = DPPF(hx, hx, 0x128, 0xF, 0xF);
    float r3 = DPPF(hx, hx, 0x12C, 0xF, 0xF);
    float A1 = fmaf(hx, W0, xpv);
    float B1 = r1 * W1;
    float A2 = fmaf(r2, W2, A1);
    float B2 = fmaf(r3, W3, B1);
    float ang = A2 + B2;

    float cv = __builtin_amdgcn_cosf(ang);   // input in revolutions

    // segmented prefix product over k (quads within row16): row_shr 4 then 8
    float sA = DPPF(one, cv, 0x114, 0xF, 0xE);   // k==0 lanes keep 1.0
    float m1 = cv * sA;
    float sB = DPPF(one, m1, 0x118, 0xF, 0xC);   // k<2 lanes keep 1.0
    float m  = m1 * sB;

    // gate value: v = D + m*(K0 + y*(K1 + y*(K2 + y*K3))), y = m^2
    float y = m * m;
    float pp = fmaf(y, K3c, K2c);
    pp = fmaf(y, pp, K1c);
    pp = fmaf(y, pp, K0c);
    float v = fmaf(m, pp, D);

    // gather f,i,u,o within quad (quad = fixed k, lanes g=0..3)
    float vf = DPPF(v, v, 0x00, 0xF, 0xF);
    float vi = DPPF(v, v, 0x55, 0xF, 0xF);
    float vu = DPPF(v, v, 0xAA, 0xF, 0xF);
    float vo = DPPF(v, v, 0xFF, 0xF, 0xF);

    cx = fmaf(vf, cx, vi * vu);

    // hx = o * tanh(cx); tanh(cx) = 1 - 2/(e^{2cx}+1), rr = 1/(e^{2cx}+1)
    float e2 = __builtin_amdgcn_exp2f(2.885390082f * cx);
    float rr = __builtin_amdgcn_rcpf(e2 + 1.0f);
    hx = fmaf(-2.0f * vo, rr, vo);

    if (t >= t_real && lane < 16 && g == 0)
      hsh[(t - t_real) * 4 + k] = hx;    // lanes 0,4,8,12 stash the 4 comps
  }

  __syncthreads();   // single wave: drains LDS writes

  // ---- fused epilogue: logits + log_softmax, lane = tag j ----
  float* orow = out + (size_t)t_real * 64 + lane;
#pragma unroll
  for (int dt = 0; dt < CHUNK; ++dt) {
    float4 h = *(const float4*)(&hsh[dt * 4]);   // broadcast read, conflict-free
    float z = bj;
    z = fmaf(h.x, wt0, z);
    z = fmaf(h.y, wt1, z);
    z = fmaf(h.z, wt2, z);
    z = fmaf(h.w, wt3, z);
    // |z| <= ~6 -> exp safe without max-sub
    float s = __builtin_amdgcn_exp2f(z * 1.4426950408889634f);
#pragma unroll
    for (int off = 32; off > 0; off >>= 1) s += __shfl_xor(s, off, 64);
    orow[dt * 64] = z - __builtin_amdgcn_logf(s) * 0.69314718055994531f;
  }
}

extern "C" void kernel_launch(void* const* d_in, const int* in_sizes, int n_in,
                              void* d_out, int out_size, void* d_ws, size_t ws_size,
                              hipStream_t stream) {
  (void)in_sizes; (void)n_in; (void)out_size; (void)ws_size;
  const int*   sent = (const int*)  d_in[0];
  const float* emb  = (const float*)d_in[1];
  const float* Wf   = (const float*)d_in[2];
  const float* bf   = (const float*)d_in[3];
  const float* Wi   = (const float*)d_in[4];
  const float* bi   = (const float*)d_in[5];
  const float* Wu   = (const float*)d_in[6];
  const float* bu   = (const float*)d_in[7];
  const float* Wo   = (const float*)d_in[8];
  const float* bo   = (const float*)d_in[9];
  const float* qf   = (const float*)d_in[10];
  const float* qi   = (const float*)d_in[11];
  const float* qu   = (const float*)d_in[12];
  const float* qo   = (const float*)d_in[13];
  const float* Wt   = (const float*)d_in[14];
  const float* bt   = (const float*)d_in[15];

  float* xp  = (float*)d_ws + WS_XP;
  float* out = (float*)d_out;

  k1_xp<<<dim3(256),  dim3(256), 0, stream>>>(sent, emb, Wf, Wi, Wu, Wo,
                                              bf, bi, bu, bo, xp);
  k2_rec<<<dim3(NCHUNK), dim3(64), 0, stream>>>(xp, Wf, Wi, Wu, Wo,
                                                qf, qi, qu, qo, Wt, bt, out);
}

// Round 5
// 173.963 us; speedup vs baseline: 1.3258x; 1.0391x over previous
//
#include <hip/hip_runtime.h>
#include <hip/hip_bf16.h>

#define N_Q    4
#define SEQ    4096
#define EMB    512
#define TAGS   64
#define INV2PI 0.15915494309189535f
#define CHUNK  8
#define WARM   20
#define NCHUNK (SEQ / CHUNK)   // 512

// ---- workspace layout (float offsets) ----
// xp : [4100][16] x-part preacts (revolutions), padded +4 steps for prefetch
#define WS_XP 0

// DPP helper: update_dpp on float via bitcast. Masked-out lanes keep OLD.
#define DPPF(OLD, SRC, CTRL, RM, BM) \
  __int_as_float(__builtin_amdgcn_update_dpp(__float_as_int(OLD), __float_as_int(SRC), (CTRL), (RM), (BM), false))

// ---------------- K1: xpart[t][p] = (emb[sent[t]] . Wcol + b) / 2pi ------
// One block = 16 timesteps x 16 columns. W staged to LDS (stride 516: 2-way
// bank aliasing only = free), scale folded into the store.
__global__ __launch_bounds__(256) void k1_xp(
    const int* __restrict__ sent, const float* __restrict__ emb,
    const float* __restrict__ Wf, const float* __restrict__ Wi,
    const float* __restrict__ Wu, const float* __restrict__ Wo,
    const float* __restrict__ bf, const float* __restrict__ bi,
    const float* __restrict__ bu, const float* __restrict__ bo,
    float* __restrict__ xp)
{
  __shared__ float colbuf[16 * 516];   // 33 KB
  int tid = threadIdx.x;
#pragma unroll
  for (int g = 0; g < 4; ++g) {
    const float* W = (g == 0) ? Wf : (g == 1) ? Wi : (g == 2) ? Wu : Wo;
#pragma unroll
    for (int half = 0; half < 2; ++half) {
      int e = tid + half * 256;
      float4 r = *(const float4*)(W + e * 4);   // row e, all 4 cols
      colbuf[(g * 4 + 0) * 516 + e] = r.x;
      colbuf[(g * 4 + 1) * 516 + e] = r.y;
      colbuf[(g * 4 + 2) * 516 + e] = r.z;
      colbuf[(g * 4 + 3) * 516 + e] = r.w;
    }
  }
  __syncthreads();

  int t = blockIdx.x * 16 + (tid >> 4);
  int c = tid & 15;                    // c = g*4+k
  int g = c >> 2, k = c & 3;
  const float4* x = (const float4*)(emb + (size_t)sent[t] * EMB);
  const float4* w = (const float4*)(&colbuf[c * 516]);   // 16B-aligned (516*4=2064)
  float a0 = 0.f, a1 = 0.f, a2 = 0.f, a3 = 0.f;
#pragma unroll 8
  for (int e4 = 0; e4 < EMB / 4; ++e4) {
    float4 xv = x[e4];
    float4 wv = w[e4];
    a0 = fmaf(xv.x, wv.x, a0);
    a1 = fmaf(xv.y, wv.y, a1);
    a2 = fmaf(xv.z, wv.z, a2);
    a3 = fmaf(xv.w, wv.w, a3);
  }
  const float* b = (g == 0) ? bf : (g == 1) ? bi : (g == 2) ? bu : bo;
  float dot = ((a0 + a1) + (a2 + a3) + b[k]) * INV2PI;
  // store at position p = k*4+g so that lane p of k2 reads its own value
  int p = ((c & 3) << 2) | (c >> 2);
  xp[t * 16 + p] = dot;
}

// ---------------- K2: recurrence + fused logits/log_softmax epilogue -----
// lane p = k*4+g : component k = p>>2, gate g = p&3 (f,i,u,o)
__global__ __launch_bounds__(64) void k2_rec(
    const float* __restrict__ xp,
    const float* __restrict__ Wf, const float* __restrict__ Wi,
    const float* __restrict__ Wu, const float* __restrict__ Wo,
    const float* __restrict__ qf, const float* __restrict__ qi,
    const float* __restrict__ qu, const float* __restrict__ qo,
    const float* __restrict__ Wt, const float* __restrict__ bt,
    float* __restrict__ out)
{
  __shared__ float hsh[CHUNK * 4];
  const int lane = threadIdx.x & 63;
  const int p = lane & 15;
  const int k = p >> 2;
  const int g = p & 3;
  const float* W = (g == 0) ? Wf : (g == 1) ? Wi : (g == 2) ? Wu : Wo;
  const float* q = (g == 0) ? qf : (g == 1) ? qi : (g == 2) ? qu : qo;

  // epilogue constants (independent loads, hidden under recurrence)
  float wt0 = Wt[lane], wt1 = Wt[64 + lane], wt2 = Wt[128 + lane], wt3 = Wt[192 + lane];
  float bj = bt[lane];

  // hx-coefficients: wh[m] = W[(512+m)*4 + k] / 2pi   (column k of own gate)
  float wh0 = W[(EMB + 0) * 4 + k] * INV2PI;
  float wh1 = W[(EMB + 1) * 4 + k] * INV2PI;
  float wh2 = W[(EMB + 2) * 4 + k] * INV2PI;
  float wh3 = W[(EMB + 3) * 4 + k] * INV2PI;

  // probe which component arrives via each row_ror (direction-robust)
  int s1i = __builtin_amdgcn_update_dpp(k, k, 0x124, 0xF, 0xF, false); // ror 4
  int s2i = __builtin_amdgcn_update_dpp(k, k, 0x128, 0xF, 0xF, false); // ror 8
  int s3i = __builtin_amdgcn_update_dpp(k, k, 0x12C, 0xF, 0xF, false); // ror 12
  #define SELW(KK) ((KK) == 0 ? wh0 : (KK) == 1 ? wh1 : (KK) == 2 ? wh2 : wh3)
  float W0 = SELW(k);
  float W1 = SELW(s1i);
  float W2 = SELW(s2i);
  float W3 = SELW(s3i);

  // cumulative cos(q) product up to own k
  float cc0 = cosf(q[0]);
  float cc1 = cc0 * cosf(q[1]);
  float cc2 = cc1 * cosf(q[2]);
  float cc3 = cc2 * cosf(q[3]);
  float cq = (k == 0) ? cc0 : (k == 1) ? cc1 : (k == 2) ? cc2 : cc3;

  // odd-poly nonlinearity coeffs (sigmoid for f,i,o; tanh for u), cq folded in
  float P0, P1, P2, P3, D;
  if (g == 2) { // tanh, max err ~2e-4 on [-1,1]
    P0 = 0.99990143f; P1 = -0.33104735f; P2 = 0.12044012f; P3 = -0.02770000f; D = 0.0f;
  } else {      // sigmoid Taylor deg-7, max err ~2e-5 on [-1,1]
    P0 = 0.25f; P1 = -0.020833334f; P2 = 0.0020833334f; P3 = -2.1081349e-4f; D = 0.5f;
  }
  float cq2 = cq * cq;
  float K0c = P0 * cq;
  float K1c = P1 * cq * cq2;
  float K2c = P2 * cq * cq2 * cq2;
  float K3c = P3 * cq * cq2 * cq2 * cq2;

  // chunk range (warmup from zero state; contraction f<=sigma(1)=0.731:
  // cx init err <=2.07 decays to 2.07*0.731^20 ~ 3.9e-3 -> logit err ~6e-3)
  int c_id = blockIdx.x;
  int t_real = c_id * CHUNK;
  int t0 = t_real - WARM; if (t0 < 0) t0 = 0;
  int t_end = t_real + CHUNK;

  const float* base = xp + p;
  float xb0 = base[t0 * 16];
  float xb1 = base[(t0 + 1) * 16];
  float xb2 = base[(t0 + 2) * 16];

  float hx = 0.f, cx = 0.f;
  const float one = 1.0f;

  for (int t = t0; t < t_end; ++t) {
    float xpv = xb0; xb0 = xb1; xb1 = xb2;
    xb2 = base[(t + 3) * 16];            // padded overread, value unused past end

    // ang (revolutions) = xp + sum_m hx_m * wh_m, via quad rotations (tree)
    float r1 = DPPF(hx, hx, 0x124, 0xF, 0xF);
    float r2 = DPPF(hx, hx, 0x128, 0xF, 0xF);
    float r3 = DPPF(hx, hx, 0x12C, 0xF, 0xF);
    float A1 = fmaf(hx, W0, xpv);
    float B1 = r1 * W1;
    float A2 = fmaf(r2, W2, A1);
    float B2 = fmaf(r3, W3, B1);
    float ang = A2 + B2;

    float cv = __builtin_amdgcn_cosf(ang);   // input in revolutions

    // segmented prefix product over k (quads within row16): row_shr 4 then 8
    float sA = DPPF(one, cv, 0x114, 0xF, 0xE);   // k==0 lanes keep 1.0
    float m1 = cv * sA;
    float sB = DPPF(one, m1, 0x118, 0xF, 0xC);   // k<2 lanes keep 1.0
    float m  = m1 * sB;

    // gate value: v = D + m*(K0 + y*(K1 + y*(K2 + y*K3))), y = m^2
    float y = m * m;
    float pp = fmaf(y, K3c, K2c);
    pp = fmaf(y, pp, K1c);
    pp = fmaf(y, pp, K0c);
    float v = fmaf(m, pp, D);

    // gather f,i,u,o within quad (quad = fixed k, lanes g=0..3)
    float vf = DPPF(v, v, 0x00, 0xF, 0xF);
    float vi = DPPF(v, v, 0x55, 0xF, 0xF);
    float vu = DPPF(v, v, 0xAA, 0xF, 0xF);
    float vo = DPPF(v, v, 0xFF, 0xF, 0xF);

    cx = fmaf(vf, cx, vi * vu);

    // hx = o * tanh(cx); tanh(cx) = 1 - 2/(e^{2cx}+1), rr = 1/(e^{2cx}+1)
    float e2 = __builtin_amdgcn_exp2f(2.885390082f * cx);
    float rr = __builtin_amdgcn_rcpf(e2 + 1.0f);
    hx = fmaf(-2.0f * vo, rr, vo);

    if (t >= t_real && lane < 16 && g == 0)
      hsh[(t - t_real) * 4 + k] = hx;    // lanes 0,4,8,12 stash the 4 comps
  }

  __syncthreads();   // single wave: drains LDS writes

  // ---- fused epilogue: logits + log_softmax, lane = tag j ----
  float* orow = out + (size_t)t_real * 64 + lane;
#pragma unroll
  for (int dt = 0; dt < CHUNK; ++dt) {
    float4 h = *(const float4*)(&hsh[dt * 4]);   // broadcast read, conflict-free
    float z = bj;
    z = fmaf(h.x, wt0, z);
    z = fmaf(h.y, wt1, z);
    z = fmaf(h.z, wt2, z);
    z = fmaf(h.w, wt3, z);
    // |z| <= ~6 -> exp safe without max-sub
    float s = __builtin_amdgcn_exp2f(z * 1.4426950408889634f);
#pragma unroll
    for (int off = 32; off > 0; off >>= 1) s += __shfl_xor(s, off, 64);
    orow[dt * 64] = z - __builtin_amdgcn_logf(s) * 0.69314718055994531f;
  }
}

extern "C" void kernel_launch(void* const* d_in, const int* in_sizes, int n_in,
                              void* d_out, int out_size, void* d_ws, size_t ws_size,
                              hipStream_t stream) {
  (void)in_sizes; (void)n_in; (void)out_size; (void)ws_size;
  const int*   sent = (const int*)  d_in[0];
  const float* emb  = (const float*)d_in[1];
  const float* Wf   = (const float*)d_in[2];
  const float* bf   = (const float*)d_in[3];
  const float* Wi   = (const float*)d_in[4];
  const float* bi   = (const float*)d_in[5];
  const float* Wu   = (const float*)d_in[6];
  const float* bu   = (const float*)d_in[7];
  const float* Wo   = (const float*)d_in[8];
  const float* bo   = (const float*)d_in[9];
  const float* qf   = (const float*)d_in[10];
  const float* qi   = (const float*)d_in[11];
  const float* qu   = (const float*)d_in[12];
  const float* qo   = (const float*)d_in[13];
  const float* Wt   = (const float*)d_in[14];
  const float* bt   = (const float*)d_in[15];

  float* xp  = (float*)d_ws + WS_XP;
  float* out = (float*)d_out;

  k1_xp<<<dim3(256),  dim3(256), 0, stream>>>(sent, emb, Wf, Wi, Wu, Wo,
                                              bf, bi, bu, bo, xp);
  k2_rec<<<dim3(NCHUNK), dim3(64), 0, stream>>>(xp, Wf, Wi, Wu, Wo,
                                                qf, qi, qu, qo, Wt, bt, out);
}